// Round 2
// baseline (982.769 us; speedup 1.0000x reference)
//
#include <hip/hip_runtime.h>

#define NN 100000
#define NE 1600000
#define CH 128
#define NG 512
#define OUTC 11

// ---------------------------------------------------------------------------
// init: zero the atomically-accumulated arrays (ws is poisoned 0xAA each call)
__global__ void init_kernel(float* __restrict__ deg, int* __restrict__ cnt,
                            int* __restrict__ fill) {
    int i = blockIdx.x * 256 + threadIdx.x;
    if (i < NN) { deg[i] = 0.0f; cnt[i] = 0; fill[i] = 0; }
}

// per-edge: accumulate weighted in-degree (f32) and in-degree count (int)
__global__ void edge_deg_kernel(const int* __restrict__ ei, const float* __restrict__ ew,
                                float* __restrict__ deg, int* __restrict__ cnt) {
    int e = blockIdx.x * 256 + threadIdx.x;
    if (e >= NE) return;
    int col = ei[NE + e];
    atomicAdd(&deg[col], ew[e]);
    atomicAdd(&cnt[col], 1);
}

// dis = 1/sqrt(deg+1); selfw = dis^2
__global__ void dis_kernel(const float* __restrict__ deg, float* __restrict__ dis,
                           float* __restrict__ selfw) {
    int i = blockIdx.x * 256 + threadIdx.x;
    if (i >= NN) return;
    float d = deg[i] + 1.0f;
    float r = 1.0f / sqrtf(d);
    dis[i] = r;
    selfw[i] = r * r;
}

// ---- exclusive scan of cnt[NN] -> colptr[NN+1] (3-kernel hierarchical) ----
__global__ void scan1_kernel(const int* __restrict__ cnt, int* __restrict__ excl,
                             int* __restrict__ bsum) {
    __shared__ int s[256];
    int t = threadIdx.x;
    int i = blockIdx.x * 256 + t;
    int v = (i < NN) ? cnt[i] : 0;
    s[t] = v;
    __syncthreads();
    #pragma unroll
    for (int off = 1; off < 256; off <<= 1) {
        int x = (t >= off) ? s[t - off] : 0;
        __syncthreads();
        s[t] += x;
        __syncthreads();
    }
    if (i < NN) excl[i] = s[t] - v;
    if (t == 255) bsum[blockIdx.x] = s[255];
}

#define SCAN_NB 391  // ceil(100000/256)

__global__ void scan2_kernel(const int* __restrict__ bsum, int* __restrict__ boff) {
    __shared__ int s[512];
    int t = threadIdx.x;
    int v = (t < SCAN_NB) ? bsum[t] : 0;
    s[t] = v;
    __syncthreads();
    #pragma unroll
    for (int off = 1; off < 512; off <<= 1) {
        int x = (t >= off) ? s[t - off] : 0;
        __syncthreads();
        s[t] += x;
        __syncthreads();
    }
    if (t < SCAN_NB) boff[t] = s[t] - v;
}

__global__ void scan3_kernel(const int* __restrict__ excl, const int* __restrict__ boff,
                             int* __restrict__ colptr) {
    int i = blockIdx.x * 256 + threadIdx.x;
    if (i < NN) colptr[i] = excl[i] + boff[i >> 8];
    if (i == 0) colptr[NN] = NE;
}

// fill CSR: csr_row[pos] = src node; csr_val[pos] = dis[row]*ew*dis[col]
__global__ void fill_kernel(const int* __restrict__ ei, const float* __restrict__ ew,
                            const float* __restrict__ dis, const int* __restrict__ colptr,
                            int* __restrict__ fill, int* __restrict__ csr_row,
                            float* __restrict__ csr_val) {
    int e = blockIdx.x * 256 + threadIdx.x;
    if (e >= NE) return;
    int row = ei[e];
    int col = ei[NE + e];
    int pos = colptr[col] + atomicAdd(&fill[col], 1);
    csr_row[pos] = row;
    csr_val[pos] = dis[row] * ew[e] * dis[col];
}

// graph boundaries in sorted batch: starts[g] = lower_bound(batch, g)
__global__ void starts_kernel(const int* __restrict__ batch, int* __restrict__ starts) {
    int g = blockIdx.x * 256 + threadIdx.x;
    if (g > NG) return;
    int lo = 0, hi = NN;
    while (lo < hi) {
        int mid = (lo + hi) >> 1;
        if (batch[mid] < g) lo = mid + 1; else hi = mid;
    }
    starts[g] = lo;
}

// ---------------------------------------------------------------------------
// f32 GEMM: C[M,128] = A[M,128] @ W[128,128].  128-row tile/block, 256 thr,
// 8x8 register micro-tile, K staged in panels of 32 (A transposed in LDS).
#define BM 128
#define BK 32

__global__ __launch_bounds__(256, 4) void gemm_kernel(const float* __restrict__ A,
                                                      const float* __restrict__ W,
                                                      float* __restrict__ C, int M) {
    __shared__ float At[BK][132];   // [k][row], padded stride (132*4B, 16B-aligned)
    __shared__ float Wp[BK][CH];    // [k][col]
    const int tid = threadIdx.x;
    const int row0 = blockIdx.x * BM;
    const int tc = (tid & 15) * 8;  // col start (16 thread-cols x 8)
    const int tr = (tid >> 4) * 8;  // row start (16 thread-rows x 8)

    float acc[8][8];
    #pragma unroll
    for (int i = 0; i < 8; ++i)
        #pragma unroll
        for (int j = 0; j < 8; ++j) acc[i][j] = 0.0f;

    for (int kk = 0; kk < CH; kk += BK) {
        // stage W panel: 32x128 floats = 1024 float4
        #pragma unroll
        for (int i = 0; i < 4; ++i) {
            int f4 = i * 256 + tid;
            int k = f4 >> 5;
            int c4 = (f4 & 31) * 4;
            *reinterpret_cast<float4*>(&Wp[k][c4]) =
                *reinterpret_cast<const float4*>(&W[(kk + k) * CH + c4]);
        }
        // stage A panel transposed: rows row0..+127, k kk..+31
        #pragma unroll
        for (int i = 0; i < 4; ++i) {
            int f4 = i * 256 + tid;
            int r = f4 >> 3;
            int kp = (f4 & 7) * 4;
            float4 a4 = make_float4(0.f, 0.f, 0.f, 0.f);
            int grow = row0 + r;
            if (grow < M)
                a4 = *reinterpret_cast<const float4*>(&A[grow * CH + kk + kp]);
            At[kp + 0][r] = a4.x;
            At[kp + 1][r] = a4.y;
            At[kp + 2][r] = a4.z;
            At[kp + 3][r] = a4.w;
        }
        __syncthreads();
        #pragma unroll 4
        for (int k = 0; k < BK; ++k) {
            float a[8], w[8];
            *reinterpret_cast<float4*>(&a[0]) = *reinterpret_cast<const float4*>(&At[k][tr]);
            *reinterpret_cast<float4*>(&a[4]) = *reinterpret_cast<const float4*>(&At[k][tr + 4]);
            *reinterpret_cast<float4*>(&w[0]) = *reinterpret_cast<const float4*>(&Wp[k][tc]);
            *reinterpret_cast<float4*>(&w[4]) = *reinterpret_cast<const float4*>(&Wp[k][tc + 4]);
            #pragma unroll
            for (int i = 0; i < 8; ++i)
                #pragma unroll
                for (int j = 0; j < 8; ++j)
                    acc[i][j] = fmaf(a[i], w[j], acc[i][j]);
        }
        __syncthreads();
    }
    #pragma unroll
    for (int i = 0; i < 8; ++i) {
        int grow = row0 + tr + i;
        if (grow < M) {
            float4 v0 = make_float4(acc[i][0], acc[i][1], acc[i][2], acc[i][3]);
            float4 v1 = make_float4(acc[i][4], acc[i][5], acc[i][6], acc[i][7]);
            *reinterpret_cast<float4*>(&C[grow * CH + tc]) = v0;
            *reinterpret_cast<float4*>(&C[grow * CH + tc + 4]) = v1;
        }
    }
}

// ---------------------------------------------------------------------------
// aggregation: one wave per destination node, float2/lane (512B coalesced row
// gather per edge), register accumulate, + bias, relu. Unroll-by-2 so two
// independent row gathers are in flight (MLP for the latency-bound tail).
__global__ __launch_bounds__(256) void agg_kernel(const float* __restrict__ hW,
                                                  const int* __restrict__ colptr,
                                                  const int* __restrict__ csr_row,
                                                  const float* __restrict__ csr_val,
                                                  const float* __restrict__ selfw,
                                                  const float* __restrict__ bias,
                                                  float* __restrict__ out) {
    const int wave = threadIdx.x >> 6;
    const int lane = threadIdx.x & 63;
    const int node = blockIdx.x * 4 + wave;
    if (node >= NN) return;
    const int c0 = lane * 2;

    float2 selfv = *reinterpret_cast<const float2*>(&hW[(size_t)node * CH + c0]);
    float sw = selfw[node];
    float accx = sw * selfv.x;
    float accy = sw * selfv.y;

    int e0 = colptr[node];
    int e1 = colptr[node + 1];
    int e = e0;
    for (; e + 1 < e1; e += 2) {
        int r0 = csr_row[e];
        int r1 = csr_row[e + 1];
        float v0 = csr_val[e];
        float v1 = csr_val[e + 1];
        float2 h0 = *reinterpret_cast<const float2*>(&hW[(size_t)r0 * CH + c0]);
        float2 h1 = *reinterpret_cast<const float2*>(&hW[(size_t)r1 * CH + c0]);
        accx = fmaf(v0, h0.x, accx);
        accy = fmaf(v0, h0.y, accy);
        accx = fmaf(v1, h1.x, accx);
        accy = fmaf(v1, h1.y, accy);
    }
    if (e < e1) {
        int r = csr_row[e];
        float v = csr_val[e];
        float2 h2 = *reinterpret_cast<const float2*>(&hW[(size_t)r * CH + c0]);
        accx = fmaf(v, h2.x, accx);
        accy = fmaf(v, h2.y, accy);
    }
    float2 b2 = *reinterpret_cast<const float2*>(&bias[c0]);
    float ox = accx + b2.x; ox = ox > 0.0f ? ox : 0.0f;
    float oy = accy + b2.y; oy = oy > 0.0f ? oy : 0.0f;
    *reinterpret_cast<float2*>(&out[(size_t)node * CH + c0]) = make_float2(ox, oy);
}

// ---------------------------------------------------------------------------
// mean pool per graph (batch sorted -> contiguous node ranges)
__global__ __launch_bounds__(128) void pool_kernel(const float* __restrict__ feat,
                                                   const int* __restrict__ starts,
                                                   float* __restrict__ pooled) {
    int g = blockIdx.x;
    int c = threadIdx.x;
    int s = starts[g], e = starts[g + 1];
    float acc = 0.0f;
    for (int n = s; n < e; ++n) acc += feat[(size_t)n * CH + c];
    pooled[g * CH + c] = acc / fmaxf((float)(e - s), 1.0f);
}

// final FC: out[g,o] = pooled[g,:] @ fcW[:,o] + fcb[o]
// 16 graphs / block (64 threads: 16 x 4-lane groups would complicate; keep
// simple: 16 graphs x 11 outs = 176 threads of 192)
__global__ __launch_bounds__(192) void fc_kernel(const float* __restrict__ pooled,
                                                 const float* __restrict__ fcW,
                                                 const float* __restrict__ fcb,
                                                 float* __restrict__ out) {
    int g = blockIdx.x * 16 + threadIdx.x / 12;
    int o = threadIdx.x % 12;
    if (g >= NG || o >= OUTC) return;
    float acc = fcb[o];
    #pragma unroll 8
    for (int c = 0; c < CH; ++c)
        acc = fmaf(pooled[g * CH + c], fcW[c * OUTC + o], acc);
    out[g * OUTC + o] = acc;
}

// ---------------------------------------------------------------------------
extern "C" void kernel_launch(void* const* d_in, const int* in_sizes, int n_in,
                              void* d_out, int out_size, void* d_ws, size_t ws_size,
                              hipStream_t stream) {
    const float* x      = (const float*)d_in[0];
    const int*   ei     = (const int*)d_in[1];
    const int*   batch  = (const int*)d_in[2];
    const float* ew     = (const float*)d_in[3];
    const float* W1     = (const float*)d_in[4];
    const float* b1     = (const float*)d_in[5];
    const float* W2     = (const float*)d_in[6];
    const float* b2     = (const float*)d_in[7];
    const float* W3     = (const float*)d_in[8];
    const float* b3     = (const float*)d_in[9];
    const float* fcW    = (const float*)d_in[10];
    const float* fcb    = (const float*)d_in[11];
    float* out = (float*)d_out;

    // workspace carve-up (256B aligned)
    char* p = (char*)d_ws;
    auto alloc = [&](size_t bytes) {
        void* r = (void*)p;
        p += (bytes + 255) & ~(size_t)255;
        return r;
    };
    float* featA   = (float*)alloc((size_t)NN * CH * 4);
    float* featB   = (float*)alloc((size_t)NN * CH * 4);
    float* deg     = (float*)alloc(NN * 4);
    float* dis     = (float*)alloc(NN * 4);
    float* selfw   = (float*)alloc(NN * 4);
    int*   cnt     = (int*)alloc(NN * 4);
    int*   excl    = (int*)alloc(NN * 4);
    int*   bsum    = (int*)alloc(SCAN_NB * 4);
    int*   boff    = (int*)alloc(SCAN_NB * 4);
    int*   colptr  = (int*)alloc((NN + 1) * 4);
    int*   fill    = (int*)alloc(NN * 4);
    int*   csr_row = (int*)alloc((size_t)NE * 4);
    float* csr_val = (float*)alloc((size_t)NE * 4);
    int*   starts  = (int*)alloc((NG + 1) * 4);
    float* pooled  = (float*)alloc((size_t)NG * CH * 4);

    const int nb_nodes = (NN + 255) / 256;      // 391
    const int nb_edges = (NE + 255) / 256;      // 6250
    const int nb_gemm  = (NN + BM - 1) / BM;    // 782
    const int nb_agg   = (NN + 3) / 4;          // 25000

    // preprocessing (once per call; reused by all 3 layers)
    init_kernel<<<nb_nodes, 256, 0, stream>>>(deg, cnt, fill);
    edge_deg_kernel<<<nb_edges, 256, 0, stream>>>(ei, ew, deg, cnt);
    dis_kernel<<<nb_nodes, 256, 0, stream>>>(deg, dis, selfw);
    scan1_kernel<<<SCAN_NB, 256, 0, stream>>>(cnt, excl, bsum);
    scan2_kernel<<<1, 512, 0, stream>>>(bsum, boff);
    scan3_kernel<<<nb_nodes, 256, 0, stream>>>(excl, boff, colptr);
    fill_kernel<<<nb_edges, 256, 0, stream>>>(ei, ew, dis, colptr, fill, csr_row, csr_val);
    starts_kernel<<<3, 256, 0, stream>>>(batch, starts);

    // layer 1: x -> featA -> featB
    gemm_kernel<<<nb_gemm, 256, 0, stream>>>(x, W1, featA, NN);
    agg_kernel<<<nb_agg, 256, 0, stream>>>(featA, colptr, csr_row, csr_val, selfw, b1, featB);
    // layer 2: featB -> featA -> featB
    gemm_kernel<<<nb_gemm, 256, 0, stream>>>(featB, W2, featA, NN);
    agg_kernel<<<nb_agg, 256, 0, stream>>>(featA, colptr, csr_row, csr_val, selfw, b2, featB);
    // layer 3
    gemm_kernel<<<nb_gemm, 256, 0, stream>>>(featB, W3, featA, NN);
    agg_kernel<<<nb_agg, 256, 0, stream>>>(featA, colptr, csr_row, csr_val, selfw, b3, featB);

    // pool + fc
    pool_kernel<<<NG, 128, 0, stream>>>(featB, starts, pooled);
    fc_kernel<<<(NG + 15) / 16, 192, 0, stream>>>(pooled, fcW, fcb, out);
}

// Round 8
// 834.667 us; speedup vs baseline: 1.1774x; 1.1774x over previous
//
#include <hip/hip_runtime.h>

#define NN 100000
#define NE 1600000
#define CH 128
#define NG 512
#define OUTC 11

// ---------------------------------------------------------------------------
// init: zero the atomic counter array (ws is poisoned 0xAA each call)
__global__ void init_kernel(int* __restrict__ cnt) {
    int i = blockIdx.x * 256 + threadIdx.x;
    if (i < NN) cnt[i] = 0;
}

// ---- exclusive scan of cnt[NN] -> colptr[NN+1] (3-kernel hierarchical) ----
__global__ void scan1_kernel(const int* __restrict__ cnt, int* __restrict__ excl,
                             int* __restrict__ bsum) {
    __shared__ int s[256];
    int t = threadIdx.x;
    int i = blockIdx.x * 256 + t;
    int v = (i < NN) ? cnt[i] : 0;
    s[t] = v;
    __syncthreads();
    #pragma unroll
    for (int off = 1; off < 256; off <<= 1) {
        int x = (t >= off) ? s[t - off] : 0;
        __syncthreads();
        s[t] += x;
        __syncthreads();
    }
    if (i < NN) excl[i] = s[t] - v;
    if (t == 255) bsum[blockIdx.x] = s[255];
}

#define SCAN_NB 391  // ceil(100000/256)

__global__ void scan2_kernel(const int* __restrict__ bsum, int* __restrict__ boff) {
    __shared__ int s[512];
    int t = threadIdx.x;
    int v = (t < SCAN_NB) ? bsum[t] : 0;
    s[t] = v;
    __syncthreads();
    #pragma unroll
    for (int off = 1; off < 512; off <<= 1) {
        int x = (t >= off) ? s[t - off] : 0;
        __syncthreads();
        s[t] += x;
        __syncthreads();
    }
    if (t < SCAN_NB) boff[t] = s[t] - v;
}

__global__ void scan3_kernel(const int* __restrict__ excl, const int* __restrict__ boff,
                             int* __restrict__ colptr) {
    int i = blockIdx.x * 256 + threadIdx.x;
    if (i < NN) colptr[i] = excl[i] + boff[i >> 8];
    if (i == 0) colptr[NN] = NE;
}

// scatter (atomic-free): csr[pos] = {src row, raw edge weight}
__global__ void scatter_kernel(const int* __restrict__ ei, const float* __restrict__ ew,
                               const int* __restrict__ colptr, const int* __restrict__ rankv,
                               int2* __restrict__ csr) {
    int e = blockIdx.x * 256 + threadIdx.x;   // grid is exactly NE/256
    int row = ei[e];
    int col = ei[NE + e];
    int pos = colptr[col] + rankv[e];
    csr[pos] = make_int2(row, __float_as_int(ew[e]));
}

// per-node: deg = sum of segment ew (contiguous, no atomics); dis = 1/sqrt(deg+1)
__global__ void deg_dis_kernel(const int* __restrict__ colptr, const int2* __restrict__ csr,
                               float* __restrict__ dis, float* __restrict__ selfw) {
    int i = blockIdx.x * 256 + threadIdx.x;
    if (i >= NN) return;
    int s = colptr[i], t = colptr[i + 1];
    float sum = 0.0f;
    for (int p = s; p < t; ++p) sum += __int_as_float(csr[p].y);
    float d = sum + 1.0f;
    float r = 1.0f / sqrtf(d);
    dis[i] = r;
    selfw[i] = r * r;
}

// per-node: csr[p].y <- dis[row] * ew * dis[col]  (in place)
__global__ void val_kernel(const int* __restrict__ colptr, const float* __restrict__ dis,
                           int2* __restrict__ csr) {
    int i = blockIdx.x * 256 + threadIdx.x;
    if (i >= NN) return;
    float dn = dis[i];
    int s = colptr[i], t = colptr[i + 1];
    for (int p = s; p < t; ++p) {
        int2 v = csr[p];
        csr[p].y = __float_as_int(dis[v.x] * __int_as_float(v.y) * dn);
    }
}

// graph boundaries in sorted batch: starts[g] = lower_bound(batch, g)
__global__ void starts_kernel(const int* __restrict__ batch, int* __restrict__ starts) {
    int g = blockIdx.x * 256 + threadIdx.x;
    if (g > NG) return;
    int lo = 0, hi = NN;
    while (lo < hi) {
        int mid = (lo + hi) >> 1;
        if (batch[mid] < g) lo = mid + 1; else hi = mid;
    }
    starts[g] = lo;
}

// ---------------------------------------------------------------------------
// f32 GEMM tile body: C[M,128] = A[M,128] @ W[128,128]. 128-row tile, 256 thr,
// 8x8 register micro-tile, K staged in panels of 32 (A transposed in LDS).
#define BM 128
#define BK 32

__device__ __forceinline__ void gemm_tile_body(const float* __restrict__ A,
                                               const float* __restrict__ W,
                                               float* __restrict__ C, int M, int blk) {
    __shared__ float At[BK][132];   // [k][row], padded stride
    __shared__ float Wp[BK][CH];    // [k][col]
    const int tid = threadIdx.x;
    const int row0 = blk * BM;
    const int tc = (tid & 15) * 8;  // col start (16 thread-cols x 8)
    const int tr = (tid >> 4) * 8;  // row start (16 thread-rows x 8)

    float acc[8][8];
    #pragma unroll
    for (int i = 0; i < 8; ++i)
        #pragma unroll
        for (int j = 0; j < 8; ++j) acc[i][j] = 0.0f;

    for (int kk = 0; kk < CH; kk += BK) {
        #pragma unroll
        for (int i = 0; i < 4; ++i) {
            int f4 = i * 256 + tid;
            int k = f4 >> 5;
            int c4 = (f4 & 31) * 4;
            *reinterpret_cast<float4*>(&Wp[k][c4]) =
                *reinterpret_cast<const float4*>(&W[(kk + k) * CH + c4]);
        }
        #pragma unroll
        for (int i = 0; i < 4; ++i) {
            int f4 = i * 256 + tid;
            int r = f4 >> 3;
            int kp = (f4 & 7) * 4;
            float4 a4 = make_float4(0.f, 0.f, 0.f, 0.f);
            int grow = row0 + r;
            if (grow < M)
                a4 = *reinterpret_cast<const float4*>(&A[grow * CH + kk + kp]);
            At[kp + 0][r] = a4.x;
            At[kp + 1][r] = a4.y;
            At[kp + 2][r] = a4.z;
            At[kp + 3][r] = a4.w;
        }
        __syncthreads();
        #pragma unroll 4
        for (int k = 0; k < BK; ++k) {
            float a[8], w[8];
            *reinterpret_cast<float4*>(&a[0]) = *reinterpret_cast<const float4*>(&At[k][tr]);
            *reinterpret_cast<float4*>(&a[4]) = *reinterpret_cast<const float4*>(&At[k][tr + 4]);
            *reinterpret_cast<float4*>(&w[0]) = *reinterpret_cast<const float4*>(&Wp[k][tc]);
            *reinterpret_cast<float4*>(&w[4]) = *reinterpret_cast<const float4*>(&Wp[k][tc + 4]);
            #pragma unroll
            for (int i = 0; i < 8; ++i)
                #pragma unroll
                for (int j = 0; j < 8; ++j)
                    acc[i][j] = fmaf(a[i], w[j], acc[i][j]);
        }
        __syncthreads();
    }
    #pragma unroll
    for (int i = 0; i < 8; ++i) {
        int grow = row0 + tr + i;
        if (grow < M) {
            float4 v0 = make_float4(acc[i][0], acc[i][1], acc[i][2], acc[i][3]);
            float4 v1 = make_float4(acc[i][4], acc[i][5], acc[i][6], acc[i][7]);
            *reinterpret_cast<float4*>(&C[grow * CH + tc]) = v0;
            *reinterpret_cast<float4*>(&C[grow * CH + tc + 4]) = v1;
        }
    }
}

__global__ __launch_bounds__(256, 4) void gemm_kernel(const float* __restrict__ A,
                                                      const float* __restrict__ W,
                                                      float* __restrict__ C, int M) {
    gemm_tile_body(A, W, C, M, blockIdx.x);
}

// fused: GEMM layer-1 (every 9th block) overlapped with the edge-rank atomic
// pass (other blocks). GEMM is VALU-bound, rank is atomic-latency-bound with
// VALUBusy 0.3% -- complementary pipes on co-resident CUs.
#define FUSE_NB 7032  // 782 gemm blocks + 6250 rank blocks

__global__ __launch_bounds__(256, 4) void gemm_rank_kernel(const float* __restrict__ A,
                                                           const float* __restrict__ W,
                                                           float* __restrict__ C, int M,
                                                           const int* __restrict__ ei,
                                                           int* __restrict__ cnt,
                                                           int* __restrict__ rankv) {
    int bid = blockIdx.x;
    if (bid % 9 == 0) {
        gemm_tile_body(A, W, C, M, bid / 9);
    } else {
        int r = bid - 1 - bid / 9;          // rank-block index 0..6249
        int e = r * 256 + threadIdx.x;      // exact: 6250*256 == NE
        int col = ei[NE + e];
        rankv[e] = atomicAdd(&cnt[col], 1);
    }
}

// ---------------------------------------------------------------------------
// aggregation: HALF-wave (32 lanes) per node, float4/lane (one dwordx4 covers
// the 512B row read), unroll-2 for MLP. 8 nodes per 256-thread block.
__global__ __launch_bounds__(256) void agg_kernel(const float* __restrict__ hW,
                                                  const int* __restrict__ colptr,
                                                  const int2* __restrict__ csr,
                                                  const float* __restrict__ selfw,
                                                  const float* __restrict__ bias,
                                                  float* __restrict__ out) {
    const int sub = threadIdx.x >> 5;
    const int l = threadIdx.x & 31;
    const int node = blockIdx.x * 8 + sub;
    if (node >= NN) return;
    const int c0 = l * 4;

    const float4 sv = *reinterpret_cast<const float4*>(&hW[(size_t)node * CH + c0]);
    const float sw = selfw[node];
    float ax = sw * sv.x, ay = sw * sv.y, az = sw * sv.z, aw = sw * sv.w;

    int e = colptr[node];
    const int e1 = colptr[node + 1];
    for (; e + 1 < e1; e += 2) {
        int2 p0 = csr[e];
        int2 p1 = csr[e + 1];
        float4 h0 = *reinterpret_cast<const float4*>(&hW[(size_t)p0.x * CH + c0]);
        float4 h1 = *reinterpret_cast<const float4*>(&hW[(size_t)p1.x * CH + c0]);
        float v0 = __int_as_float(p0.y);
        float v1 = __int_as_float(p1.y);
        ax = fmaf(v0, h0.x, ax); ay = fmaf(v0, h0.y, ay);
        az = fmaf(v0, h0.z, az); aw = fmaf(v0, h0.w, aw);
        ax = fmaf(v1, h1.x, ax); ay = fmaf(v1, h1.y, ay);
        az = fmaf(v1, h1.z, az); aw = fmaf(v1, h1.w, aw);
    }
    if (e < e1) {
        int2 p0 = csr[e];
        float4 h0 = *reinterpret_cast<const float4*>(&hW[(size_t)p0.x * CH + c0]);
        float v0 = __int_as_float(p0.y);
        ax = fmaf(v0, h0.x, ax); ay = fmaf(v0, h0.y, ay);
        az = fmaf(v0, h0.z, az); aw = fmaf(v0, h0.w, aw);
    }
    const float4 b = *reinterpret_cast<const float4*>(&bias[c0]);
    float ox = fmaxf(ax + b.x, 0.0f);
    float oy = fmaxf(ay + b.y, 0.0f);
    float oz = fmaxf(az + b.z, 0.0f);
    float ow = fmaxf(aw + b.w, 0.0f);
    *reinterpret_cast<float4*>(&out[(size_t)node * CH + c0]) = make_float4(ox, oy, oz, ow);
}

// ---------------------------------------------------------------------------
// mean pool per graph (batch sorted -> contiguous node ranges)
__global__ __launch_bounds__(128) void pool_kernel(const float* __restrict__ feat,
                                                   const int* __restrict__ starts,
                                                   float* __restrict__ pooled) {
    int g = blockIdx.x;
    int c = threadIdx.x;
    int s = starts[g], e = starts[g + 1];
    float acc = 0.0f;
    for (int n = s; n < e; ++n) acc += feat[(size_t)n * CH + c];
    pooled[g * CH + c] = acc / fmaxf((float)(e - s), 1.0f);
}

// final FC: out[g,o] = pooled[g,:] @ fcW[:,o] + fcb[o]
__global__ __launch_bounds__(192) void fc_kernel(const float* __restrict__ pooled,
                                                 const float* __restrict__ fcW,
                                                 const float* __restrict__ fcb,
                                                 float* __restrict__ out) {
    int g = blockIdx.x * 16 + threadIdx.x / 12;
    int o = threadIdx.x % 12;
    if (g >= NG || o >= OUTC) return;
    float acc = fcb[o];
    #pragma unroll 8
    for (int c = 0; c < CH; ++c)
        acc = fmaf(pooled[g * CH + c], fcW[c * OUTC + o], acc);
    out[g * OUTC + o] = acc;
}

// ---------------------------------------------------------------------------
extern "C" void kernel_launch(void* const* d_in, const int* in_sizes, int n_in,
                              void* d_out, int out_size, void* d_ws, size_t ws_size,
                              hipStream_t stream) {
    const float* x      = (const float*)d_in[0];
    const int*   ei     = (const int*)d_in[1];
    const int*   batch  = (const int*)d_in[2];
    const float* ew     = (const float*)d_in[3];
    const float* W1     = (const float*)d_in[4];
    const float* b1     = (const float*)d_in[5];
    const float* W2     = (const float*)d_in[6];
    const float* b2     = (const float*)d_in[7];
    const float* W3     = (const float*)d_in[8];
    const float* b3     = (const float*)d_in[9];
    const float* fcW    = (const float*)d_in[10];
    const float* fcb    = (const float*)d_in[11];
    float* out = (float*)d_out;

    // workspace carve-up (256B aligned)
    char* p = (char*)d_ws;
    auto alloc = [&](size_t bytes) {
        void* r = (void*)p;
        p += (bytes + 255) & ~(size_t)255;
        return r;
    };
    float* featA   = (float*)alloc((size_t)NN * CH * 4);
    float* featB   = (float*)alloc((size_t)NN * CH * 4);
    int*   cnt     = (int*)alloc(NN * 4);
    int*   rankv   = (int*)alloc((size_t)NE * 4);
    int*   excl    = (int*)alloc(NN * 4);
    int*   bsum    = (int*)alloc(SCAN_NB * 4);
    int*   boff    = (int*)alloc(SCAN_NB * 4);
    int*   colptr  = (int*)alloc((NN + 1) * 4);
    int2*  csr     = (int2*)alloc((size_t)NE * 8);
    float* dis     = (float*)alloc(NN * 4);
    float* selfw   = (float*)alloc(NN * 4);
    int*   starts  = (int*)alloc((NG + 1) * 4);
    float* pooled  = (float*)alloc((size_t)NG * CH * 4);

    const int nb_nodes = (NN + 255) / 256;      // 391
    const int nb_edges = (NE + 255) / 256;      // 6250
    const int nb_gemm  = (NN + BM - 1) / BM;    // 782
    const int nb_agg   = NN / 8;                // 12500 (8 nodes/block)

    // preprocessing (reused by all 3 layers); gemm1 overlapped with rank pass
    init_kernel<<<nb_nodes, 256, 0, stream>>>(cnt);
    gemm_rank_kernel<<<FUSE_NB, 256, 0, stream>>>(x, W1, featA, NN, ei, cnt, rankv);
    scan1_kernel<<<SCAN_NB, 256, 0, stream>>>(cnt, excl, bsum);
    scan2_kernel<<<1, 512, 0, stream>>>(bsum, boff);
    scan3_kernel<<<nb_nodes, 256, 0, stream>>>(excl, boff, colptr);
    scatter_kernel<<<nb_edges, 256, 0, stream>>>(ei, ew, colptr, rankv, csr);
    deg_dis_kernel<<<nb_nodes, 256, 0, stream>>>(colptr, csr, dis, selfw);
    val_kernel<<<nb_nodes, 256, 0, stream>>>(colptr, dis, csr);
    starts_kernel<<<3, 256, 0, stream>>>(batch, starts);

    // layer 1 aggregation (gemm1 already done in fused kernel)
    agg_kernel<<<nb_agg, 256, 0, stream>>>(featA, colptr, csr, selfw, b1, featB);
    // layer 2
    gemm_kernel<<<nb_gemm, 256, 0, stream>>>(featB, W2, featA, NN);
    agg_kernel<<<nb_agg, 256, 0, stream>>>(featA, colptr, csr, selfw, b2, featB);
    // layer 3
    gemm_kernel<<<nb_gemm, 256, 0, stream>>>(featB, W3, featA, NN);
    agg_kernel<<<nb_agg, 256, 0, stream>>>(featA, colptr, csr, selfw, b3, featB);

    // pool + fc
    pool_kernel<<<NG, 128, 0, stream>>>(featB, starts, pooled);
    fc_kernel<<<(NG + 15) / 16, 192, 0, stream>>>(pooled, fcW, fcb, out);
}